// Round 1
// baseline (741.305 us; speedup 1.0000x reference)
//
#include <hip/hip_runtime.h>

#define NG 8192
#define NC 4096
#define FG 512
#define FC 256
#define ALPHA 0.2f

typedef float f32x4 __attribute__((ext_vector_type(4)));
typedef short bf16x8 __attribute__((ext_vector_type(8)));

static __device__ __forceinline__ float leakyf(float x) { return fmaxf(x, ALPHA * x); }

static __device__ __forceinline__ unsigned short f2bf(float f) {
    unsigned u = __builtin_bit_cast(unsigned, f);
    u += 0x7fffu + ((u >> 16) & 1u);          // RNE; w>=0, no NaN here
    return (unsigned short)(u >> 16);
}

static __device__ __forceinline__ float wred(float v) {
#pragma unroll
    for (int m = 1; m < 64; m <<= 1) v += __shfl_xor(v, m, 64);
    return v;
}

// ---------------- projection: h = x@W  [N,K]@[K,64], + bf16 h^T, + 5 per-node scalars
__global__ __launch_bounds__(256) void proj_kernel(
    const float* __restrict__ x, const float* __restrict__ W, int K, int N,
    float* __restrict__ h, unsigned short* __restrict__ hT,
    const float* __restrict__ aA, const float* __restrict__ aB,
    const float* __restrict__ aC, const float* __restrict__ aD,
    const float* __restrict__ aG, const float* __restrict__ bG,
    float* __restrict__ sA, float* __restrict__ sB, float* __restrict__ sC,
    float* __restrict__ sD, float* __restrict__ gam)
{
    const int wave = threadIdx.x >> 6, lane = threadIdx.x & 63;
    const int r0 = blockIdx.x * 16 + wave * 4;     // 4 rows per wave
    const float* xr = x + (size_t)r0 * K;
    float acc0 = 0.f, acc1 = 0.f, acc2 = 0.f, acc3 = 0.f;
    for (int k = 0; k < K; k += 4) {
        float4 x0 = *(const float4*)(xr + k);
        float4 x1 = *(const float4*)(xr + K + k);
        float4 x2 = *(const float4*)(xr + 2 * (size_t)K + k);
        float4 x3 = *(const float4*)(xr + 3 * (size_t)K + k);
        float w0 = W[(k + 0) * 64 + lane];
        float w1 = W[(k + 1) * 64 + lane];
        float w2 = W[(k + 2) * 64 + lane];
        float w3 = W[(k + 3) * 64 + lane];
        acc0 += x0.x * w0 + x0.y * w1 + x0.z * w2 + x0.w * w3;
        acc1 += x1.x * w0 + x1.y * w1 + x1.z * w2 + x1.w * w3;
        acc2 += x2.x * w0 + x2.y * w1 + x2.z * w2 + x2.w * w3;
        acc3 += x3.x * w0 + x3.y * w1 + x3.z * w2 + x3.w * w3;
    }
    float accs[4] = {acc0, acc1, acc2, acc3};
    unsigned short hb[4];
#pragma unroll
    for (int t = 0; t < 4; t++) {
        h[(size_t)(r0 + t) * 64 + lane] = accs[t];
        hb[t] = f2bf(accs[t]);
    }
    *(ushort4*)&hT[(size_t)lane * N + r0] = make_ushort4(hb[0], hb[1], hb[2], hb[3]);

    const float cA = aA[lane], cB = aB[lane], cC = aC[lane], cD = aD[lane], cG = aG[lane];
    const float bias = bG[0];
#pragma unroll
    for (int t = 0; t < 4; t++) {
        float vA = wred(accs[t] * cA);
        float vB = wred(accs[t] * cB);
        float vC = wred(accs[t] * cC);
        float vD = wred(accs[t] * cD);
        float vG = wred(accs[t] * cG);
        if (lane == 0) {
            sA[r0 + t] = vA; sB[r0 + t] = vB; sC[r0 + t] = vC; sD[r0 + t] = vD;
            gam[r0 + t] = 1.f / (1.f + __expf(-(vG + bias)));
        }
    }
}

// ---------------- relation: partial num[p][i][0:64] and l[p][i] over j-range
// w_ij = adj ? exp(leaky(s1_i + s2_j)) : 0 ;  num_i = sum_j w_ij * h_dst[j]
__global__ __launch_bounds__(256) void rel_kernel(
    const int* __restrict__ adj, int adj_ld, int transposed,
    const float* __restrict__ s1, const float* __restrict__ s2,
    const unsigned short* __restrict__ hT, int Nd,
    float* __restrict__ num, float* __restrict__ lsum, int Ns, int JS)
{
    __shared__ unsigned short lds[64 * 264];        // 33792 B, stride 264 avoids ds_read_b128 quad conflicts
    const int wave = threadIdx.x >> 6, lane = threadIdx.x & 63;
    const int m = lane & 15, kp = lane >> 4;
    const int strip = blockIdx.x, p = blockIdx.y;
    const int jlen = Nd / JS;
    const int jbase = p * jlen;
    const int i_row = strip * 64 + wave * 16 + m;
    const float s1v = s1[i_row];
    f32x4 acc0 = {0.f, 0.f, 0.f, 0.f}, acc1 = acc0, acc2 = acc0, acc3 = acc0;
    float lacc = 0.f;

    for (int j0 = jbase; j0 < jbase + jlen; j0 += 256) {
        // stage h_dst^T chunk [64 cols][256 j] into LDS
        for (int idx = threadIdx.x; idx < 2048; idx += 256) {
            int c = idx >> 5, off = (idx & 31) * 8;
            *(int4*)&lds[c * 264 + off] = *(const int4*)&hT[(size_t)c * Nd + j0 + off];
        }
        __syncthreads();
#pragma unroll
        for (int kk = 0; kk < 8; kk++) {
            const int jg = j0 + kk * 32 + kp * 8;
            float s2v[8];
            {
                float4 sa = *(const float4*)&s2[jg];
                float4 sb = *(const float4*)&s2[jg + 4];
                s2v[0] = sa.x; s2v[1] = sa.y; s2v[2] = sa.z; s2v[3] = sa.w;
                s2v[4] = sb.x; s2v[5] = sb.y; s2v[6] = sb.z; s2v[7] = sb.w;
            }
            int am[8];
            if (!transposed) {
                const int* ar = adj + (size_t)i_row * adj_ld + jg;
                int4 a0 = *(const int4*)ar;
                int4 a1 = *(const int4*)(ar + 4);
                am[0] = a0.x; am[1] = a0.y; am[2] = a0.z; am[3] = a0.w;
                am[4] = a1.x; am[5] = a1.y; am[6] = a1.z; am[7] = a1.w;
            } else {
                const int* ac = adj + (size_t)jg * adj_ld + i_row;
#pragma unroll
                for (int t = 0; t < 8; t++) am[t] = ac[(size_t)t * adj_ld];
            }
            bf16x8 af;
#pragma unroll
            for (int t = 0; t < 8; t++) {
                float e = s1v + s2v[t];
                float w = (am[t] > 0) ? __expf(leakyf(e)) : 0.f;
                lacc += w;
                af[t] = (short)f2bf(w);
            }
            const int lb = kk * 32 + kp * 8;
            bf16x8 b0 = *(const bf16x8*)&lds[(0 * 16 + m) * 264 + lb];
            bf16x8 b1 = *(const bf16x8*)&lds[(1 * 16 + m) * 264 + lb];
            bf16x8 b2 = *(const bf16x8*)&lds[(2 * 16 + m) * 264 + lb];
            bf16x8 b3 = *(const bf16x8*)&lds[(3 * 16 + m) * 264 + lb];
            acc0 = __builtin_amdgcn_mfma_f32_16x16x32_bf16(af, b0, acc0, 0, 0, 0);
            acc1 = __builtin_amdgcn_mfma_f32_16x16x32_bf16(af, b1, acc1, 0, 0, 0);
            acc2 = __builtin_amdgcn_mfma_f32_16x16x32_bf16(af, b2, acc2, 0, 0, 0);
            acc3 = __builtin_amdgcn_mfma_f32_16x16x32_bf16(af, b3, acc3, 0, 0, 0);
        }
        __syncthreads();
    }
    // C/D layout: col = lane&15 (+16g), row = (lane>>4)*4 + r
    const int orow0 = strip * 64 + wave * 16 + kp * 4;
#pragma unroll
    for (int r = 0; r < 4; r++) {
        size_t base = ((size_t)p * Ns + orow0 + r) * 64;
        num[base + m]      = acc0[r];
        num[base + 16 + m] = acc1[r];
        num[base + 32 + m] = acc2[r];
        num[base + 48 + m] = acc3[r];
    }
    lacc += __shfl_xor(lacc, 16, 64);
    lacc += __shfl_xor(lacc, 32, 64);
    if (kp == 0) lsum[(size_t)p * Ns + strip * 64 + wave * 16 + m] = lacc;
}

// ---------------- combine partials -> R  (R = num/l)
__global__ __launch_bounds__(256) void combine_store(
    const float* __restrict__ num, const float* __restrict__ l,
    int Ns, int JS, float* __restrict__ R)
{
    int idx = blockIdx.x * 256 + threadIdx.x;
    int i = idx >> 6, c = idx & 63;
    float n = 0.f, d = 0.f;
    for (int p = 0; p < JS; p++) {
        n += num[((size_t)p * Ns + i) * 64 + c];
        d += l[(size_t)p * Ns + i];
    }
    R[idx] = n / d;
}

// ---------------- combine + final epilogue: out = leaky(h + Rself + gamma*Rcross)
__global__ __launch_bounds__(256) void combine_final(
    const float* __restrict__ num, const float* __restrict__ l,
    int Ns, int JS, const float* __restrict__ h, const float* __restrict__ Rself,
    const float* __restrict__ gam, float* __restrict__ out)
{
    int idx = blockIdx.x * 256 + threadIdx.x;
    int i = idx >> 6, c = idx & 63;
    float n = 0.f, d = 0.f;
    for (int p = 0; p < JS; p++) {
        n += num[((size_t)p * Ns + i) * 64 + c];
        d += l[(size_t)p * Ns + i];
    }
    float v = h[idx] + Rself[idx] + gam[i] * (n / d);
    out[idx] = leakyf(v);
}

extern "C" void kernel_launch(void* const* d_in, const int* in_sizes, int n_in,
                              void* d_out, int out_size, void* d_ws, size_t ws_size,
                              hipStream_t stream)
{
    const float* gene_x = (const float*)d_in[0];
    const float* cell_x = (const float*)d_in[1];
    const float* W_g    = (const float*)d_in[2];
    const float* W_c    = (const float*)d_in[3];
    const float* a_gg   = (const float*)d_in[4];
    const float* a_gc   = (const float*)d_in[5];
    const float* a_cc   = (const float*)d_in[6];
    const float* a_cg   = (const float*)d_in[7];
    const float* Wgg    = (const float*)d_in[8];
    const float* bgg    = (const float*)d_in[9];
    const float* Wgc    = (const float*)d_in[10];
    const float* bgc    = (const float*)d_in[11];
    const int* gene_adj = (const int*)d_in[12];
    const int* cell_adj = (const int*)d_in[13];
    const int* gc_adj   = (const int*)d_in[14];

    size_t off = 0;
    char* wsb = (char*)d_ws;
    auto alloc = [&](size_t bytes) -> void* {
        void* p = wsb + off;
        off += (bytes + 255) & ~(size_t)255;
        return p;
    };
    float* gene_h = (float*)alloc((size_t)NG * 64 * 4);
    float* cell_h = (float*)alloc((size_t)NC * 64 * 4);
    unsigned short* gene_hT = (unsigned short*)alloc((size_t)NG * 64 * 2);
    unsigned short* cell_hT = (unsigned short*)alloc((size_t)NC * 64 * 2);
    float* s1gg = (float*)alloc(NG * 4);
    float* s2gg = (float*)alloc(NG * 4);
    float* s1gc = (float*)alloc(NG * 4);
    float* s2cg = (float*)alloc(NG * 4);
    float* gamg = (float*)alloc(NG * 4);
    float* s1cc = (float*)alloc(NC * 4);
    float* s2cc = (float*)alloc(NC * 4);
    float* s2gc = (float*)alloc(NC * 4);
    float* s1cg = (float*)alloc(NC * 4);
    float* gamc = (float*)alloc(NC * 4);
    float* Rgg  = (float*)alloc((size_t)NG * 64 * 4);
    float* Rcc  = (float*)alloc((size_t)NC * 64 * 4);
    float* numA = (float*)alloc((size_t)NG * 64 * 4 * 4);   // 8 MB  (JS=4, Ns=8192)
    float* lA   = (float*)alloc((size_t)NG * 4 * 4);
    float* numB = (float*)alloc((size_t)NC * 64 * 8 * 4);   // 8 MB  (JS=8, Ns=4096)
    float* lB   = (float*)alloc((size_t)NC * 8 * 4);

    float* out_gene = (float*)d_out;
    float* out_cell = (float*)d_out + (size_t)NG * 64;

    // projections (+ per-node scalars)
    proj_kernel<<<NG / 16, 256, 0, stream>>>(gene_x, W_g, FG, NG, gene_h, gene_hT,
        a_gg, a_gg + 64, a_gc, a_cg + 64, Wgg, bgg, s1gg, s2gg, s1gc, s2cg, gamg);
    proj_kernel<<<NC / 16, 256, 0, stream>>>(cell_x, W_c, FC, NC, cell_h, cell_hT,
        a_cc, a_cc + 64, a_gc + 64, a_cg, Wgc, bgc, s1cc, s2cc, s2gc, s1cg, gamc);

    // gene<-gene (adj 256 MB)
    rel_kernel<<<dim3(NG / 64, 4), 256, 0, stream>>>(gene_adj, NG, 0, s1gg, s2gg,
        gene_hT, NG, numA, lA, NG, 4);
    combine_store<<<NG * 64 / 256, 256, 0, stream>>>(numA, lA, NG, 4, Rgg);

    // cell<-cell (adj 64 MB)
    rel_kernel<<<dim3(NC / 64, 8), 256, 0, stream>>>(cell_adj, NC, 0, s1cc, s2cc,
        cell_hT, NC, numB, lB, NC, 8);
    combine_store<<<NC * 64 / 256, 256, 0, stream>>>(numB, lB, NC, 8, Rcc);

    // gene<-cell then cell<-gene back-to-back so gc_adj (128 MB) stays L3-resident
    rel_kernel<<<dim3(NG / 64, 4), 256, 0, stream>>>(gc_adj, NC, 0, s1gc, s2gc,
        cell_hT, NC, numA, lA, NG, 4);
    rel_kernel<<<dim3(NC / 64, 8), 256, 0, stream>>>(gc_adj, NC, 1, s1cg, s2cg,
        gene_hT, NG, numB, lB, NC, 8);

    combine_final<<<NG * 64 / 256, 256, 0, stream>>>(numA, lA, NG, 4, gene_h, Rgg, gamg, out_gene);
    combine_final<<<NC * 64 / 256, 256, 0, stream>>>(numB, lB, NC, 8, cell_h, Rcc, gamc, out_cell);
}

// Round 2
// 729.380 us; speedup vs baseline: 1.0164x; 1.0164x over previous
//
#include <hip/hip_runtime.h>

#define NG 8192
#define NC 4096
#define FG 512
#define FC 256
#define ALPHA 0.2f

typedef float f32x4 __attribute__((ext_vector_type(4)));
typedef short bf16x8 __attribute__((ext_vector_type(8)));

static __device__ __forceinline__ float leakyf(float x) { return fmaxf(x, ALPHA * x); }

static __device__ __forceinline__ unsigned short f2bf(float f) {
    unsigned u = __builtin_bit_cast(unsigned, f);
    u += 0x7fffu + ((u >> 16) & 1u);          // RNE; w>=0, no NaN here
    return (unsigned short)(u >> 16);
}

static __device__ __forceinline__ float wred(float v) {
#pragma unroll
    for (int m = 1; m < 64; m <<= 1) v += __shfl_xor(v, m, 64);
    return v;
}

// ---------------- projection: h = x@W  [N,K]@[K,64], + bf16 h^T, + 5 per-node scalars
__global__ __launch_bounds__(256) void proj_kernel(
    const float* __restrict__ x, const float* __restrict__ W, int K, int N,
    float* __restrict__ h, unsigned short* __restrict__ hT,
    const float* __restrict__ aA, const float* __restrict__ aB,
    const float* __restrict__ aC, const float* __restrict__ aD,
    const float* __restrict__ aG, const float* __restrict__ bG,
    float* __restrict__ sA, float* __restrict__ sB, float* __restrict__ sC,
    float* __restrict__ sD, float* __restrict__ gam)
{
    const int wave = threadIdx.x >> 6, lane = threadIdx.x & 63;
    const int r0 = blockIdx.x * 16 + wave * 4;     // 4 rows per wave
    const float* xr = x + (size_t)r0 * K;
    float acc0 = 0.f, acc1 = 0.f, acc2 = 0.f, acc3 = 0.f;
    for (int k = 0; k < K; k += 4) {
        float4 x0 = *(const float4*)(xr + k);
        float4 x1 = *(const float4*)(xr + K + k);
        float4 x2 = *(const float4*)(xr + 2 * (size_t)K + k);
        float4 x3 = *(const float4*)(xr + 3 * (size_t)K + k);
        float w0 = W[(k + 0) * 64 + lane];
        float w1 = W[(k + 1) * 64 + lane];
        float w2 = W[(k + 2) * 64 + lane];
        float w3 = W[(k + 3) * 64 + lane];
        acc0 += x0.x * w0 + x0.y * w1 + x0.z * w2 + x0.w * w3;
        acc1 += x1.x * w0 + x1.y * w1 + x1.z * w2 + x1.w * w3;
        acc2 += x2.x * w0 + x2.y * w1 + x2.z * w2 + x2.w * w3;
        acc3 += x3.x * w0 + x3.y * w1 + x3.z * w2 + x3.w * w3;
    }
    float accs[4] = {acc0, acc1, acc2, acc3};
    unsigned short hb[4];
#pragma unroll
    for (int t = 0; t < 4; t++) {
        h[(size_t)(r0 + t) * 64 + lane] = accs[t];
        hb[t] = f2bf(accs[t]);
    }
    *(ushort4*)&hT[(size_t)lane * N + r0] = make_ushort4(hb[0], hb[1], hb[2], hb[3]);

    const float cA = aA[lane], cB = aB[lane], cC = aC[lane], cD = aD[lane], cG = aG[lane];
    const float bias = bG[0];
#pragma unroll
    for (int t = 0; t < 4; t++) {
        float vA = wred(accs[t] * cA);
        float vB = wred(accs[t] * cB);
        float vC = wred(accs[t] * cC);
        float vD = wred(accs[t] * cD);
        float vG = wred(accs[t] * cG);
        if (lane == 0) {
            sA[r0 + t] = vA; sB[r0 + t] = vB; sC[r0 + t] = vC; sD[r0 + t] = vD;
            gam[r0 + t] = 1.f / (1.f + __expf(-(vG + bias)));
        }
    }
}

// ---------------- relation: partial num[p][i][0:64] and l[p][i] over j-range
// w_ij = adj ? exp(leaky(s1_i + s2_j)) : 0 ;  num_i = sum_j w_ij * h_dst[j]
// JS=16 j-splits -> 8x more blocks than R1 (occupancy/MLP was the limiter)
__global__ __launch_bounds__(256, 4) void rel_kernel(
    const int* __restrict__ adj, int adj_ld, int transposed,
    const float* __restrict__ s1, const float* __restrict__ s2,
    const unsigned short* __restrict__ hT, int Nd,
    float* __restrict__ num, float* __restrict__ lsum, int Ns, int JS)
{
    __shared__ unsigned short lds[64 * 264];        // 33792 B -> 4 blocks/CU
    const int wave = threadIdx.x >> 6, lane = threadIdx.x & 63;
    const int m = lane & 15, kp = lane >> 4;
    const int strip = blockIdx.x, p = blockIdx.y;
    const int jlen = Nd / JS;
    const int jbase = p * jlen;
    const int i_row = strip * 64 + wave * 16 + m;
    const float s1v = s1[i_row];
    f32x4 acc0 = {0.f, 0.f, 0.f, 0.f}, acc1 = acc0, acc2 = acc0, acc3 = acc0;
    float lacc = 0.f;

    for (int j0 = jbase; j0 < jbase + jlen; j0 += 256) {
        // stage h_dst^T chunk [64 cols][256 j] into LDS
        for (int idx = threadIdx.x; idx < 2048; idx += 256) {
            int c = idx >> 5, off = (idx & 31) * 8;
            *(int4*)&lds[c * 264 + off] = *(const int4*)&hT[(size_t)c * Nd + j0 + off];
        }
        __syncthreads();
#pragma unroll
        for (int kk = 0; kk < 8; kk++) {
            const int jg = j0 + kk * 32 + kp * 8;
            float s2v[8];
            {
                float4 sa = *(const float4*)&s2[jg];
                float4 sb = *(const float4*)&s2[jg + 4];
                s2v[0] = sa.x; s2v[1] = sa.y; s2v[2] = sa.z; s2v[3] = sa.w;
                s2v[4] = sb.x; s2v[5] = sb.y; s2v[6] = sb.z; s2v[7] = sb.w;
            }
            int am[8];
            if (!transposed) {
                const int* ar = adj + (size_t)i_row * adj_ld + jg;
                int4 a0 = *(const int4*)ar;
                int4 a1 = *(const int4*)(ar + 4);
                am[0] = a0.x; am[1] = a0.y; am[2] = a0.z; am[3] = a0.w;
                am[4] = a1.x; am[5] = a1.y; am[6] = a1.z; am[7] = a1.w;
            } else {
                const int* ac = adj + (size_t)jg * adj_ld + i_row;
#pragma unroll
                for (int t = 0; t < 8; t++) am[t] = ac[(size_t)t * adj_ld];
            }
            bf16x8 af;
#pragma unroll
            for (int t = 0; t < 8; t++) {
                float e = s1v + s2v[t];
                float w = (am[t] > 0) ? __expf(leakyf(e)) : 0.f;
                lacc += w;
                af[t] = (short)f2bf(w);
            }
            const int lb = kk * 32 + kp * 8;
            bf16x8 b0 = *(const bf16x8*)&lds[(0 * 16 + m) * 264 + lb];
            bf16x8 b1 = *(const bf16x8*)&lds[(1 * 16 + m) * 264 + lb];
            bf16x8 b2 = *(const bf16x8*)&lds[(2 * 16 + m) * 264 + lb];
            bf16x8 b3 = *(const bf16x8*)&lds[(3 * 16 + m) * 264 + lb];
            acc0 = __builtin_amdgcn_mfma_f32_16x16x32_bf16(af, b0, acc0, 0, 0, 0);
            acc1 = __builtin_amdgcn_mfma_f32_16x16x32_bf16(af, b1, acc1, 0, 0, 0);
            acc2 = __builtin_amdgcn_mfma_f32_16x16x32_bf16(af, b2, acc2, 0, 0, 0);
            acc3 = __builtin_amdgcn_mfma_f32_16x16x32_bf16(af, b3, acc3, 0, 0, 0);
        }
        __syncthreads();
    }
    // C/D layout: col = lane&15 (+16g), row = (lane>>4)*4 + r
    const int orow0 = strip * 64 + wave * 16 + kp * 4;
#pragma unroll
    for (int r = 0; r < 4; r++) {
        size_t base = ((size_t)p * Ns + orow0 + r) * 64;
        num[base + m]      = acc0[r];
        num[base + 16 + m] = acc1[r];
        num[base + 32 + m] = acc2[r];
        num[base + 48 + m] = acc3[r];
    }
    lacc += __shfl_xor(lacc, 16, 64);
    lacc += __shfl_xor(lacc, 32, 64);
    if (kp == 0) lsum[(size_t)p * Ns + strip * 64 + wave * 16 + m] = lacc;
}

// ---------------- fused combine + epilogue: out = leaky(h + numS/lS + gam*numX/lX)
__global__ __launch_bounds__(256) void combine_final(
    const float* __restrict__ numS, const float* __restrict__ lS, int JSS,
    const float* __restrict__ numX, const float* __restrict__ lX, int JSX,
    int Ns, const float* __restrict__ h, const float* __restrict__ gam,
    float* __restrict__ out)
{
    int idx = blockIdx.x * 256 + threadIdx.x;
    int i = idx >> 6, c = idx & 63;
    float nS = 0.f, dS = 0.f, nX = 0.f, dX = 0.f;
    for (int p = 0; p < JSS; p++) {
        nS += numS[((size_t)p * Ns + i) * 64 + c];
        dS += lS[(size_t)p * Ns + i];
    }
    for (int p = 0; p < JSX; p++) {
        nX += numX[((size_t)p * Ns + i) * 64 + c];
        dX += lX[(size_t)p * Ns + i];
    }
    float v = h[idx] + nS / dS + gam[i] * (nX / dX);
    out[idx] = leakyf(v);
}

extern "C" void kernel_launch(void* const* d_in, const int* in_sizes, int n_in,
                              void* d_out, int out_size, void* d_ws, size_t ws_size,
                              hipStream_t stream)
{
    const float* gene_x = (const float*)d_in[0];
    const float* cell_x = (const float*)d_in[1];
    const float* W_g    = (const float*)d_in[2];
    const float* W_c    = (const float*)d_in[3];
    const float* a_gg   = (const float*)d_in[4];
    const float* a_gc   = (const float*)d_in[5];
    const float* a_cc   = (const float*)d_in[6];
    const float* a_cg   = (const float*)d_in[7];
    const float* Wgg    = (const float*)d_in[8];
    const float* bgg    = (const float*)d_in[9];
    const float* Wgc    = (const float*)d_in[10];
    const float* bgc    = (const float*)d_in[11];
    const int* gene_adj = (const int*)d_in[12];
    const int* cell_adj = (const int*)d_in[13];
    const int* gc_adj   = (const int*)d_in[14];

    size_t off = 0;
    char* wsb = (char*)d_ws;
    auto alloc = [&](size_t bytes) -> void* {
        void* p = wsb + off;
        off += (bytes + 255) & ~(size_t)255;
        return p;
    };
    const int JS = 16;
    float* gene_h = (float*)alloc((size_t)NG * 64 * 4);
    float* cell_h = (float*)alloc((size_t)NC * 64 * 4);
    unsigned short* gene_hT = (unsigned short*)alloc((size_t)NG * 64 * 2);
    unsigned short* cell_hT = (unsigned short*)alloc((size_t)NC * 64 * 2);
    float* s1gg = (float*)alloc(NG * 4);
    float* s2gg = (float*)alloc(NG * 4);
    float* s1gc = (float*)alloc(NG * 4);
    float* s2cg = (float*)alloc(NG * 4);
    float* gamg = (float*)alloc(NG * 4);
    float* s1cc = (float*)alloc(NC * 4);
    float* s2cc = (float*)alloc(NC * 4);
    float* s2gc = (float*)alloc(NC * 4);
    float* s1cg = (float*)alloc(NC * 4);
    float* gamc = (float*)alloc(NC * 4);
    float* numGG = (float*)alloc((size_t)NG * 64 * JS * 4);  // 32 MB
    float* lGG   = (float*)alloc((size_t)NG * JS * 4);
    float* numGC = (float*)alloc((size_t)NG * 64 * JS * 4);  // 32 MB
    float* lGC   = (float*)alloc((size_t)NG * JS * 4);
    float* numCC = (float*)alloc((size_t)NC * 64 * JS * 4);  // 16 MB
    float* lCC   = (float*)alloc((size_t)NC * JS * 4);
    float* numCG = (float*)alloc((size_t)NC * 64 * JS * 4);  // 16 MB
    float* lCG   = (float*)alloc((size_t)NC * JS * 4);

    float* out_gene = (float*)d_out;
    float* out_cell = (float*)d_out + (size_t)NG * 64;

    // projections (+ per-node scalars)
    proj_kernel<<<NG / 16, 256, 0, stream>>>(gene_x, W_g, FG, NG, gene_h, gene_hT,
        a_gg, a_gg + 64, a_gc, a_cg + 64, Wgg, bgg, s1gg, s2gg, s1gc, s2cg, gamg);
    proj_kernel<<<NC / 16, 256, 0, stream>>>(cell_x, W_c, FC, NC, cell_h, cell_hT,
        a_cc, a_cc + 64, a_gc + 64, a_cg, Wgc, bgc, s1cc, s2cc, s2gc, s1cg, gamc);

    // 4 relations back-to-back (gc then cg keeps gc_adj L3-warm)
    rel_kernel<<<dim3(NG / 64, JS), 256, 0, stream>>>(gene_adj, NG, 0, s1gg, s2gg,
        gene_hT, NG, numGG, lGG, NG, JS);
    rel_kernel<<<dim3(NC / 64, JS), 256, 0, stream>>>(cell_adj, NC, 0, s1cc, s2cc,
        cell_hT, NC, numCC, lCC, NC, JS);
    rel_kernel<<<dim3(NG / 64, JS), 256, 0, stream>>>(gc_adj, NC, 0, s1gc, s2gc,
        cell_hT, NC, numGC, lGC, NG, JS);
    rel_kernel<<<dim3(NC / 64, JS), 256, 0, stream>>>(gc_adj, NC, 1, s1cg, s2cg,
        gene_hT, NG, numCG, lCG, NC, JS);

    // fused combine + epilogue
    combine_final<<<NG * 64 / 256, 256, 0, stream>>>(numGG, lGG, JS, numGC, lGC, JS,
        NG, gene_h, gamg, out_gene);
    combine_final<<<NC * 64 / 256, 256, 0, stream>>>(numCC, lCC, JS, numCG, lCG, JS,
        NC, cell_h, gamc, out_cell);
}